// Round 11
// baseline (644.708 us; speedup 1.0000x reference)
//
#include <hip/hip_runtime.h>
#include <hip/hip_bf16.h>

// Block_ViT on MI355X — round 23:
// (a) PV-direct: ctx = 0.25 * Vb2 @ S[b]^T as ONE K=3840 grouped mfmaGZ
//     dispatch (224 blocks, 120 fast K-steps) -> per-head tmp (48MB traffic)
//     and ctxsum dispatch eliminated. R16's idea, now on the right kernel.
// (b) prep_kernel = cvtn + ln_all merged (block-range split, 4160 blocks).
// (c) cx2 relocated to QTp pool (dead after SRest) — no Vb2 overlap in PV.
// 14 -> 12 dispatches. mfma8kv / mfma4 / mfmaGZ / mfma4g unchanged from R22.
// B=4, N=784, H=4, Cs={64,128,256,512}, KV=960, NT=3136. fp32 in/out.

using bf16 = __hip_bfloat16;
typedef __attribute__((ext_vector_type(8))) short short8;   // 8 bf16 (4 VGPRs)
typedef __attribute__((ext_vector_type(4))) float f32x4;    // MFMA acc

__device__ inline float bf2f(unsigned short u) {
    return __uint_as_float(((unsigned int)u) << 16);
}
__device__ inline unsigned short f2b(float f) {            // RTNE fp32->bf16
    unsigned int u = __float_as_uint(f);
    return (unsigned short)((u + 0x7fffu + ((u >> 16) & 1u)) >> 16);
}
__device__ inline float ld1f(const float* p) { return *p; }
__device__ inline float ld1f(const bf16* p) { return bf2f(*(const unsigned short*)p); }
__device__ inline void st1(float* p, float v) { *p = v; }
__device__ inline void st1(bf16* p, float v) { *((unsigned short*)p) = f2b(v); }
__device__ inline float4 ld4f(const bf16* p) {
    ushort4 u = *(const ushort4*)p;
    return make_float4(bf2f(u.x), bf2f(u.y), bf2f(u.z), bf2f(u.w));
}

// async global->LDS, 16 B per lane; LDS dest = wave-uniform base + lane*16
__device__ __forceinline__ void cp16(const void* g, void* l) {
    __builtin_amdgcn_global_load_lds(
        (const __attribute__((address_space(1))) void*)g,
        (__attribute__((address_space(3))) void*)l, 16, 0, 0);
}

// ---- block reductions (256 threads = 4 waves) ----
__device__ inline float blockSum256(float v, float* red) {
    #pragma unroll
    for (int o = 32; o > 0; o >>= 1) v += __shfl_down(v, o);
    int t = threadIdx.x;
    if ((t & 63) == 0) red[t >> 6] = v;
    __syncthreads();
    float r = red[0] + red[1] + red[2] + red[3];
    __syncthreads();
    return r;
}
__device__ inline float blockMax256(float v, float* red) {
    #pragma unroll
    for (int o = 32; o > 0; o >>= 1) v = fmaxf(v, __shfl_down(v, o));
    int t = threadIdx.x;
    if ((t & 63) == 0) red[t >> 6] = v;
    __syncthreads();
    float r = fmaxf(fmaxf(red[0], red[1]), fmaxf(red[2], red[3]));
    __syncthreads();
    return r;
}

// ---- merged prep: fp32->bf16 of ALL weights + stat zeroing + ln_all ----
struct CvtN {
    const float* s[18];
    unsigned short* d[18];
    long n[18];
    float* z;             // zero 128 floats (4 branches x 32 IN stats)
};
struct LNA {
    const float* e[4];
    const float* ag[4];
    const float* ab[4];
    const float* cg;
    const float* cbb;
    bf16* y[4];
    bf16* ea;
};
struct Prep { CvtN cv; LNA ln; };
__global__ __launch_bounds__(256)
void prep_kernel(Prep p) {
    __shared__ float x[960];
    __shared__ float red[4];
    if (blockIdx.x < 1024) {            // ---- weight conversion part ----
        CvtN& a = p.cv;
        if (a.z && blockIdx.x == 0 && threadIdx.x < 128) a.z[threadIdx.x] = 0.f;
        long tid = (long)blockIdx.x * 256 + threadIdx.x;
        long stride = 1024L * 256;
        for (int g = 0; g < 18; g++) {
            const float* s = a.s[g];
            unsigned short* d = a.d[g];
            long n = a.n[g];
            for (long i = tid * 4; i < n; i += stride * 4) {
                float4 v = *(const float4*)(s + i);
                *(ushort4*)(d + i) = make_ushort4(f2b(v.x), f2b(v.y), f2b(v.z), f2b(v.w));
            }
        }
        return;
    }
    // ---- ln_all part: concat-LN (ea) + 4 branch first-LNs ----
    LNA& a = p.ln;
    long row = blockIdx.x - 1024;
    int t = threadIdx.x;
    const int off[5] = {0, 64, 192, 448, 960};
    {
        const float* p1 = a.e[0] + row * 64;
        const float* p2 = a.e[1] + row * 128;
        const float* p3 = a.e[2] + row * 256;
        const float* p4 = a.e[3] + row * 512;
        if (t < 64) x[t] = p1[t];
        for (int i = t; i < 128; i += 256) x[64 + i]  = p2[i];
        for (int i = t; i < 256; i += 256) x[192 + i] = p3[i];
        for (int i = t; i < 512; i += 256) x[448 + i] = p4[i];
    }
    __syncthreads();
    float ssum[4], ssq[4];
    #pragma unroll
    for (int br = 0; br < 4; br++) {
        float s = 0.f, q = 0.f;
        for (int i = off[br] + t; i < off[br + 1]; i += 256) {
            float v = x[i]; s += v; q += v * v;
        }
        ssum[br] = blockSum256(s, red);
        ssq[br]  = blockSum256(q, red);
    }
    float S1 = ssum[0] + ssum[1] + ssum[2] + ssum[3];
    float S2 = ssq[0] + ssq[1] + ssq[2] + ssq[3];
    float muA = S1 * (1.f / 960.f);
    float rA = rsqrtf(S2 * (1.f / 960.f) - muA * muA + 1e-6f);
    for (int i = t; i < 960; i += 256)
        st1(a.ea + row * 960 + i, (x[i] - muA) * rA * a.cg[i] + a.cbb[i]);
    #pragma unroll
    for (int br = 0; br < 4; br++) {
        int C = off[br + 1] - off[br];
        float mu = ssum[br] / C;
        float rr = rsqrtf(ssq[br] / C - mu * mu + 1e-6f);
        const float* g = a.ag[br];
        const float* b = a.ab[br];
        bf16* y = a.y[br] + row * C;
        for (int i = t; i < C; i += 256)
            st1(y + i, (x[off[br] + i] - mu) * rr * g[i] + b[i]);
    }
}

// ==== mfma8kv: fused K+V projection, 256x256 tile, 8 waves, BK=64 (R21) ====
__global__ __launch_bounds__(512, 2)
void mfma8kv(const bf16* __restrict__ A, const bf16* __restrict__ B,
             bf16* __restrict__ KT, bf16* __restrict__ V) {
    __shared__ short Asl[2][2][256][32];
    __shared__ short Bsl[2][2][256][32];
    const int M = 3136, lda = 960, ldb = 960;
    int orig = (int)blockIdx.y * 32 + (int)blockIdx.x;
    int c = orig & 7, r2 = orig >> 3;
    int bx = (c & 3) * 8 + (r2 & 7);
    int by = (c >> 2) * 7 + (r2 >> 3);
    int m0 = by * 256, n0 = bx * 256;
    if (m0 >= M || n0 >= 7680) return;
    int t = threadIdx.x, lane = t & 63, wv = t >> 6;
    int col = lane & 15, quad = lane >> 4;
    int wm = wv >> 2, wn = wv & 3;
    f32x4 acc[8][4];
    #pragma unroll
    for (int i = 0; i < 8; i++)
        #pragma unroll
        for (int j = 0; j < 4; j++) acc[i][j] = (f32x4){0.f, 0.f, 0.f, 0.f};

    int srow = lane >> 2;
    int scol = ((lane & 3) ^ ((lane >> 3) & 3)) << 3;
    int rslot = (quad ^ ((col >> 1) & 3)) << 3;

    auto stageA = [&](int s2, int kt, int kh) {
        int k0 = kt * 64 + kh * 32;
        #pragma unroll
        for (int r = 0; r < 2; r++) {
            int R0 = (r * 8 + wv) * 16;
            cp16(A + (long)(m0 + R0 + srow) * lda + k0 + scol, &Asl[s2][kh][R0][0]);
        }
    };
    auto stageB = [&](int s2, int kt, int kh) {
        int k0 = kt * 64 + kh * 32;
        #pragma unroll
        for (int r = 0; r < 2; r++) {
            int R0 = (r * 8 + wv) * 16;
            cp16(B + (long)(n0 + R0 + srow) * ldb + k0 + scol, &Bsl[s2][kh][R0][0]);
        }
    };

    const int nk = 15;
    stageA(0, 0, 0); stageB(0, 0, 0); stageA(0, 0, 1); stageB(0, 0, 1);
    __syncthreads();

    for (int kt = 0; kt < nk; kt++) {
        int cur = kt & 1, nxt = cur ^ 1;
        bool st = (kt + 1 < nk);
        short8 af[8], bf8[4];
        #pragma unroll
        for (int ni = 0; ni < 4; ni++)
            bf8[ni] = *(const short8*)&Bsl[cur][0][wn * 64 + ni * 16 + col][rslot];
        #pragma unroll
        for (int mi = 0; mi < 4; mi++)
            af[mi] = *(const short8*)&Asl[cur][0][wm * 128 + mi * 16 + col][rslot];
        if (st) stageA(nxt, kt + 1, 0);
        __builtin_amdgcn_s_barrier();
        asm volatile("s_waitcnt lgkmcnt(0)" ::: "memory");
        __builtin_amdgcn_sched_barrier(0);
        __builtin_amdgcn_s_setprio(1);
        #pragma unroll
        for (int mi = 0; mi < 4; mi++)
            #pragma unroll
            for (int ni = 0; ni < 4; ni++)
                acc[mi][ni] = __builtin_amdgcn_mfma_f32_16x16x32_bf16(
                    af[mi], bf8[ni], acc[mi][ni], 0, 0, 0);
        __builtin_amdgcn_s_setprio(0);
        __builtin_amdgcn_s_barrier();
        #pragma unroll
        for (int mi = 4; mi < 8; mi++)
            af[mi] = *(const short8*)&Asl[cur][0][wm * 128 + mi * 16 + col][rslot];
        if (st) stageB(nxt, kt + 1, 0);
        __builtin_amdgcn_s_barrier();
        asm volatile("s_waitcnt lgkmcnt(0)" ::: "memory");
        __builtin_amdgcn_sched_barrier(0);
        __builtin_amdgcn_s_setprio(1);
        #pragma unroll
        for (int mi = 4; mi < 8; mi++)
            #pragma unroll
            for (int ni = 0; ni < 4; ni++)
                acc[mi][ni] = __builtin_amdgcn_mfma_f32_16x16x32_bf16(
                    af[mi], bf8[ni], acc[mi][ni], 0, 0, 0);
        __builtin_amdgcn_s_setprio(0);
        if (st) asm volatile("s_waitcnt vmcnt(4)" ::: "memory");
        else    asm volatile("s_waitcnt vmcnt(0)" ::: "memory");
        __builtin_amdgcn_s_barrier();
        #pragma unroll
        for (int ni = 0; ni < 4; ni++)
            bf8[ni] = *(const short8*)&Bsl[cur][1][wn * 64 + ni * 16 + col][rslot];
        #pragma unroll
        for (int mi = 0; mi < 4; mi++)
            af[mi] = *(const short8*)&Asl[cur][1][wm * 128 + mi * 16 + col][rslot];
        if (st) stageA(nxt, kt + 1, 1);
        __builtin_amdgcn_s_barrier();
        asm volatile("s_waitcnt lgkmcnt(0)" ::: "memory");
        __builtin_amdgcn_sched_barrier(0);
        __builtin_amdgcn_s_setprio(1);
        #pragma unroll
        for (int mi = 0; mi < 4; mi++)
            #pragma unroll
            for (int ni = 0; ni < 4; ni++)
                acc[mi][ni] = __builtin_amdgcn_mfma_f32_16x16x32_bf16(
                    af[mi], bf8[ni], acc[mi][ni], 0, 0, 0);
        __builtin_amdgcn_s_setprio(0);
        __builtin_amdgcn_s_barrier();
        #pragma unroll
        for (int mi = 4; mi < 8; mi++)
            af[mi] = *(const short8*)&Asl[cur][1][wm * 128 + mi * 16 + col][rslot];
        if (st) stageB(nxt, kt + 1, 1);
        __builtin_amdgcn_s_barrier();
        asm volatile("s_waitcnt lgkmcnt(0)" ::: "memory");
        __builtin_amdgcn_sched_barrier(0);
        __builtin_amdgcn_s_setprio(1);
        #pragma unroll
        for (int mi = 4; mi < 8; mi++)
            #pragma unroll
            for (int ni = 0; ni < 4; ni++)
                acc[mi][ni] = __builtin_amdgcn_mfma_f32_16x16x32_bf16(
                    af[mi], bf8[ni], acc[mi][ni], 0, 0, 0);
        __builtin_amdgcn_s_setprio(0);
        if (st) asm volatile("s_waitcnt vmcnt(4)" ::: "memory");
        __builtin_amdgcn_s_barrier();
    }
    #pragma unroll
    for (int mi = 0; mi < 8; mi++) {
        int gmB = m0 + wm * 128 + mi * 16 + quad * 4;
        #pragma unroll
        for (int ni = 0; ni < 4; ni++) {
            int gn = n0 + wn * 64 + ni * 16 + col;
            if (gn < 3840) {
                if (gmB < M) {
                    ushort4 w = make_ushort4(f2b(acc[mi][ni][0]), f2b(acc[mi][ni][1]),
                                             f2b(acc[mi][ni][2]), f2b(acc[mi][ni][3]));
                    *(ushort4*)((unsigned short*)KT + (long)gn * M + gmB) = w;
                }
            } else {
                int vn = gn - 3840;
                #pragma unroll
                for (int r = 0; r < 4; r++) {
                    int gm = gmB + r;
                    if (gm < M) st1(V + (long)gm * 3840 + vn, acc[mi][ni][r]);
                }
            }
        }
    }
}

// ==== mfma4: 128x128, 4 waves, BK=32, 3 LDS slots (R19, unchanged) ====
template <class CT, class RT, bool TO>
__global__ __launch_bounds__(256, 3)
void mfma4(const bf16* __restrict__ A, long Ah, long Ab, int lda,
           const bf16* __restrict__ B, long Bh, long Bb, int ldb,
           CT* __restrict__ Cp, long Ch, long Cb, int ldc,
           const float* __restrict__ bias, const RT* __restrict__ res,
           int M, int N, int K, int Mpad, int Npad, int qx, int hy,
           float alpha, int dogelu, float* __restrict__ stat) {
    __shared__ short Asl[3][128][32];
    __shared__ short Bsl[3][128][32];
    int gx = gridDim.x, gy = gridDim.y;
    int orig = ((int)blockIdx.z * gy + (int)blockIdx.y) * gx + (int)blockIdx.x;
    int bx, by, bz;
    if (qx) {
        int c = orig & 7, r2 = orig >> 3;
        bx = (c & 3) * qx + r2 % qx;
        by = (c >> 2) * hy + r2 / qx;
        bz = 0;
    } else {
        int nxy = gx * gy, nwg = nxy * (int)gridDim.z;
        int q = nwg >> 3, r8 = nwg & 7;
        int xcd = orig & 7, pos = orig >> 3;
        int wgid = (xcd < r8 ? xcd * (q + 1) : r8 * (q + 1) + (xcd - r8) * q) + pos;
        bz = wgid / nxy;
        int rem = wgid - bz * nxy;
        by = rem / gx; bx = rem - by * gx;
    }
    int z = bz;
    A += (long)(z & 3) * Ah + (long)(z >> 2) * Ab;
    B += (long)(z & 3) * Bh + (long)(z >> 2) * Bb;
    Cp += (long)(z & 3) * Ch + (long)(z >> 2) * Cb;
    int m0 = by * 128, n0 = bx * 128;
    int t = threadIdx.x, lane = t & 63, wv = t >> 6;
    int col = lane & 15, quad = lane >> 4;
    int wm = wv >> 1, wn = wv & 1;
    f32x4 acc[4][4];
    #pragma unroll
    for (int i = 0; i < 4; i++)
        #pragma unroll
        for (int j = 0; j < 4; j++) acc[i][j] = (f32x4){0.f, 0.f, 0.f, 0.f};

    const bool fA = (m0 + 128 <= Mpad);
    const bool fB = (n0 + 128 <= Npad);
    int srow = lane >> 2;
    int scol = ((lane & 3) ^ ((lane >> 3) & 3)) << 3;
    int rslot = (quad ^ ((col >> 1) & 3)) << 3;

    auto stageA = [&](int s3, int kt) {
        int k0 = kt * 32;
        if (fA && k0 + 32 <= K) {
            #pragma unroll
            for (int r = 0; r < 2; r++) {
                int R0 = (r * 4 + wv) * 16;
                cp16(A + (long)(m0 + R0 + srow) * lda + k0 + scol, &Asl[s3][R0][0]);
            }
        } else {
            #pragma unroll
            for (int r = 0; r < 2; r++) {
                int idx = r * 256 + t;
                int row = idx >> 2, sl = idx & 3;
                int f2 = (row >> 1) & 3;
                short8 v = {};
                if (m0 + row < M && k0 + sl * 8 < K)
                    v = *(const short8*)(A + (long)(m0 + row) * lda + k0 + sl * 8);
                *(short8*)&Asl[s3][row][(sl ^ f2) * 8] = v;
            }
            asm volatile("s_waitcnt lgkmcnt(0)" ::: "memory");
        }
    };
    auto stageB = [&](int s3, int kt) {
        int k0 = kt * 32;
        if (fB && k0 + 32 <= K) {
            #pragma unroll
            for (int r = 0; r < 2; r++) {
                int R0 = (r * 4 + wv) * 16;
                cp16(B + (long)(n0 + R0 + srow) * ldb + k0 + scol, &Bsl[s3][R0][0]);
            }
        } else {
            #pragma unroll
            for (int r = 0; r < 2; r++) {
                int idx = r * 256 + t;
                int row = idx >> 2, sl = idx & 3;
                int f2 = (row >> 1) & 3;
                short8 v = {};
                if (n0 + row < N && k0 + sl * 8 < K)
                    v = *(const short8*)(B + (long)(n0 + row) * ldb + k0 + sl * 8);
                *(short8*)&Bsl[s3][row][(sl ^ f2) * 8] = v;
            }
            asm volatile("s_waitcnt lgkmcnt(0)" ::: "memory");
        }
    };

    int nk = (K + 31) >> 5;
    stageA(0, 0); stageB(0, 0);
    stageA(1, 1); stageB(1, 1);
    __syncthreads();

    for (int kt = 0; kt < nk; kt++) {
        int cur = kt % 3;
        short8 af[4], bf4[4];
        #pragma unroll
        for (int mi = 0; mi < 4; mi++)
            af[mi] = *(const short8*)&Asl[cur][wm * 64 + mi * 16 + col][rslot];
        #pragma unroll
        for (int ni = 0; ni < 4; ni++)
            bf4[ni] = *(const short8*)&Bsl[cur][wn * 64 + ni * 16 + col][rslot];
        int pend = 0;
        if (kt + 2 < nk) {
            int s3 = (kt + 2) % 3;
            stageA(s3, kt + 2); stageB(s3, kt + 2);
            if ((kt + 2) * 32 + 32 <= K) pend = (fA ? 2 : 0) + (fB ? 2 : 0);
        }
        __builtin_amdgcn_s_barrier();
        asm volatile("s_waitcnt lgkmcnt(0)" ::: "memory");
        __builtin_amdgcn_sched_barrier(0);
        __builtin_amdgcn_s_setprio(1);
        #pragma unroll
        for (int mi = 0; mi < 4; mi++)
            #pragma unroll
            for (int ni = 0; ni < 4; ni++)
                acc[mi][ni] = __builtin_amdgcn_mfma_f32_16x16x32_bf16(
                    af[mi], bf4[ni], acc[mi][ni], 0, 0, 0);
        __builtin_amdgcn_s_setprio(0);
        if (kt + 1 < nk) {
            if (pend == 4)      asm volatile("s_waitcnt vmcnt(4)" ::: "memory");
            else if (pend == 2) asm volatile("s_waitcnt vmcnt(2)" ::: "memory");
            else                asm volatile("s_waitcnt vmcnt(0)" ::: "memory");
            __builtin_amdgcn_s_barrier();
        }
    }
    float psum = 0.f, psq = 0.f;
    #pragma unroll
    for (int mi = 0; mi < 4; mi++) {
        int gmB = m0 + wm * 64 + mi * 16 + quad * 4;
        #pragma unroll
        for (int ni = 0; ni < 4; ni++) {
            int gn = n0 + wn * 64 + ni * 16 + col;
            if constexpr (TO) {
                if (gmB < M && gn < N) {
                    ushort4 w = make_ushort4(f2b(acc[mi][ni][0] * alpha),
                                             f2b(acc[mi][ni][1] * alpha),
                                             f2b(acc[mi][ni][2] * alpha),
                                             f2b(acc[mi][ni][3] * alpha));
                    *(ushort4*)((unsigned short*)Cp + (long)gn * ldc + gmB) = w;
                }
            } else {
                if (gn < N) {
                    float bz2 = bias ? bias[gn] : 0.f;
                    #pragma unroll
                    for (int r = 0; r < 4; r++) {
                        int gm = gmB + r;
                        if (gm < M) {
                            float v = acc[mi][ni][r] * alpha + bz2;
                            if (dogelu) v = 0.5f * v * (1.f + erff(v * 0.70710678118f));
                            if (res) v += ld1f(res + (long)gm * ldc + gn);
                            st1(Cp + (long)gm * ldc + gn, v);
                            psum += v; psq += v * v;
                        }
                    }
                }
            }
        }
    }
    if (stat) {
        __syncthreads();
        #pragma unroll
        for (int o = 32; o > 0; o >>= 1) {
            psum += __shfl_down(psum, o);
            psq  += __shfl_down(psq, o);
        }
        float* red = (float*)Asl;
        if ((t & 63) == 0) { red[wv] = psum; red[4 + wv] = psq; }
        __syncthreads();
        if (t == 0) {
            atomicAdd(&stat[2 * z],     red[0] + red[1] + red[2] + red[3]);
            atomicAdd(&stat[2 * z + 1], red[4] + red[5] + red[6] + red[7]);
        }
    }
}

// ==== mfmaGZ: grouped (<=4) z-batched 128x128 GEMM with tails ====
// Per group: C[z] = alpha * A[z] @ B[z]^T; z-offsets (z&3)*Xh + (z>>2)*Xb.
// TO: transposed bf16 store. stat: fused IN sum/sumsq atomicAdd per z.
struct GZ {
    const bf16* A[4]; const bf16* B[4]; bf16* C[4];
    long Ah[4], Ab[4], Bh[4], Bb[4], Ch[4], Cb[4];
    int lda[4], ldb[4], ldc[4], M[4], N[4], K[4], Mpad[4], Npad[4], nbx[4], nby[4];
    float alpha[4];
    float* stat[4];
    int cum[5];
};
template <bool TO>
__global__ __launch_bounds__(256, 3)
void mfmaGZ(GZ g) {
    __shared__ short Asl[3][128][32];
    __shared__ short Bsl[3][128][32];
    int nwg = gridDim.x;
    int orig = blockIdx.x;
    int q = nwg >> 3, r8 = nwg & 7;
    int xcd = orig & 7, pos = orig >> 3;
    int wgid = (xcd < r8 ? xcd * (q + 1) : r8 * (q + 1) + (xcd - r8) * q) + pos;
    int gi = 0;
    if (wgid >= g.cum[1]) gi = 1;
    if (wgid >= g.cum[2]) gi = 2;
    if (wgid >= g.cum[3]) gi = 3;
    int local = wgid - g.cum[gi];
    int nbx = g.nbx[gi], nby = g.nby[gi];
    int z = local / (nbx * nby);
    int rem = local - z * nbx * nby;
    int by = rem / nbx, bx = rem - by * nbx;
    const bf16* A = g.A[gi] + (long)(z & 3) * g.Ah[gi] + (long)(z >> 2) * g.Ab[gi];
    const bf16* B = g.B[gi] + (long)(z & 3) * g.Bh[gi] + (long)(z >> 2) * g.Bb[gi];
    bf16* Cp = g.C[gi] + (long)(z & 3) * g.Ch[gi] + (long)(z >> 2) * g.Cb[gi];
    int lda = g.lda[gi], ldb = g.ldb[gi], ldc = g.ldc[gi];
    int M = g.M[gi], N = g.N[gi], K = g.K[gi];
    int Mpad = g.Mpad[gi], Npad = g.Npad[gi];
    float alpha = g.alpha[gi];
    float* stat = g.stat[gi];

    int m0 = by * 128, n0 = bx * 128;
    int t = threadIdx.x, lane = t & 63, wv = t >> 6;
    int col = lane & 15, quad = lane >> 4;
    int wm = wv >> 1, wn = wv & 1;
    f32x4 acc[4][4];
    #pragma unroll
    for (int i = 0; i < 4; i++)
        #pragma unroll
        for (int j = 0; j < 4; j++) acc[i][j] = (f32x4){0.f, 0.f, 0.f, 0.f};

    const bool fA = (m0 + 128 <= Mpad);
    const bool fB = (n0 + 128 <= Npad);
    int srow = lane >> 2;
    int scol = ((lane & 3) ^ ((lane >> 3) & 3)) << 3;
    int rslot = (quad ^ ((col >> 1) & 3)) << 3;

    auto stageA = [&](int s3, int kt) {
        int k0 = kt * 32;
        if (fA && k0 + 32 <= K) {
            #pragma unroll
            for (int r = 0; r < 2; r++) {
                int R0 = (r * 4 + wv) * 16;
                cp16(A + (long)(m0 + R0 + srow) * lda + k0 + scol, &Asl[s3][R0][0]);
            }
        } else {
            #pragma unroll
            for (int r = 0; r < 2; r++) {
                int idx = r * 256 + t;
                int row = idx >> 2, sl = idx & 3;
                int f2 = (row >> 1) & 3;
                short8 v = {};
                if (m0 + row < M && k0 + sl * 8 < K)
                    v = *(const short8*)(A + (long)(m0 + row) * lda + k0 + sl * 8);
                *(short8*)&Asl[s3][row][(sl ^ f2) * 8] = v;
            }
            asm volatile("s_waitcnt lgkmcnt(0)" ::: "memory");
        }
    };
    auto stageB = [&](int s3, int kt) {
        int k0 = kt * 32;
        if (fB && k0 + 32 <= K) {
            #pragma unroll
            for (int r = 0; r < 2; r++) {
                int R0 = (r * 4 + wv) * 16;
                cp16(B + (long)(n0 + R0 + srow) * ldb + k0 + scol, &Bsl[s3][R0][0]);
            }
        } else {
            #pragma unroll
            for (int r = 0; r < 2; r++) {
                int idx = r * 256 + t;
                int row = idx >> 2, sl = idx & 3;
                int f2 = (row >> 1) & 3;
                short8 v = {};
                if (n0 + row < N && k0 + sl * 8 < K)
                    v = *(const short8*)(B + (long)(n0 + row) * ldb + k0 + sl * 8);
                *(short8*)&Bsl[s3][row][(sl ^ f2) * 8] = v;
            }
            asm volatile("s_waitcnt lgkmcnt(0)" ::: "memory");
        }
    };

    int nk = (K + 31) >> 5;
    stageA(0, 0); stageB(0, 0);
    stageA(1, 1); stageB(1, 1);
    __syncthreads();

    for (int kt = 0; kt < nk; kt++) {
        int cur = kt % 3;
        short8 af[4], bf4[4];
        #pragma unroll
        for (int mi = 0; mi < 4; mi++)
            af[mi] = *(const short8*)&Asl[cur][wm * 64 + mi * 16 + col][rslot];
        #pragma unroll
        for (int ni = 0; ni < 4; ni++)
            bf4[ni] = *(const short8*)&Bsl[cur][wn * 64 + ni * 16 + col][rslot];
        int pend = 0;
        if (kt + 2 < nk) {
            int s3 = (kt + 2) % 3;
            stageA(s3, kt + 2); stageB(s3, kt + 2);
            if ((kt + 2) * 32 + 32 <= K) pend = (fA ? 2 : 0) + (fB ? 2 : 0);
        }
        __builtin_amdgcn_s_barrier();
        asm volatile("s_waitcnt lgkmcnt(0)" ::: "memory");
        __builtin_amdgcn_sched_barrier(0);
        __builtin_amdgcn_s_setprio(1);
        #pragma unroll
        for (int mi = 0; mi < 4; mi++)
            #pragma unroll
            for (int ni = 0; ni < 4; ni++)
                acc[mi][ni] = __builtin_amdgcn_mfma_f32_16x16x32_bf16(
                    af[mi], bf4[ni], acc[mi][ni], 0, 0, 0);
        __builtin_amdgcn_s_setprio(0);
        if (kt + 1 < nk) {
            if (pend == 4)      asm volatile("s_waitcnt vmcnt(4)" ::: "memory");
            else if (pend == 2) asm volatile("s_waitcnt vmcnt(2)" ::: "memory");
            else                asm volatile("s_waitcnt vmcnt(0)" ::: "memory");
            __builtin_amdgcn_s_barrier();
        }
    }
    float psum = 0.f, psq = 0.f;
    #pragma unroll
    for (int mi = 0; mi < 4; mi++) {
        int gmB = m0 + wm * 64 + mi * 16 + quad * 4;
        #pragma unroll
        for (int ni = 0; ni < 4; ni++) {
            int gn = n0 + wn * 64 + ni * 16 + col;
            if constexpr (TO) {
                if (gmB < M && gn < N) {
                    ushort4 w = make_ushort4(f2b(acc[mi][ni][0] * alpha),
                                             f2b(acc[mi][ni][1] * alpha),
                                             f2b(acc[mi][ni][2] * alpha),
                                             f2b(acc[mi][ni][3] * alpha));
                    *(ushort4*)((unsigned short*)Cp + (long)gn * ldc + gmB) = w;
                }
            } else {
                if (gn < N) {
                    #pragma unroll
                    for (int r = 0; r < 4; r++) {
                        int gm = gmB + r;
                        if (gm < M) {
                            float v = acc[mi][ni][r] * alpha;
                            st1(Cp + (long)gm * ldc + gn, v);
                            psum += v; psq += v * v;
                        }
                    }
                }
            }
        }
    }
    if (stat) {
        __syncthreads();
        #pragma unroll
        for (int o = 32; o > 0; o >>= 1) {
            psum += __shfl_down(psum, o);
            psq  += __shfl_down(psq, o);
        }
        float* red = (float*)Asl;
        if ((t & 63) == 0) { red[wv] = psum; red[4 + wv] = psq; }
        __syncthreads();
        if (t == 0) {
            atomicAdd(&stat[2 * z],     red[0] + red[1] + red[2] + red[3]);
            atomicAdd(&stat[2 * z + 1], red[4] + red[5] + red[6] + red[7]);
        }
    }
}

// ==== mfma4g: grouped (4-problem) 128x128 GEMM, pure fast path (R20) ====
struct G4 {
    const bf16* A[4]; const bf16* B[4]; void* Cv[4];
    const float* bias[4]; const void* res[4];
    int M[4], N[4], K[4], lda[4], ldb[4], ldc[4], nbx[4];
    int cum[5];
};
template <class CT, class RT>
__global__ __launch_bounds__(256, 3)
void mfma4g(G4 gp, int dogelu) {
    __shared__ short Asl[3][128][32];
    __shared__ short Bsl[3][128][32];
    int nwg = gridDim.x;
    int orig = blockIdx.x;
    int q = nwg >> 3, r8 = nwg & 7;
    int xcd = orig & 7, pos = orig >> 3;
    int wgid = (xcd < r8 ? xcd * (q + 1) : r8 * (q + 1) + (xcd - r8) * q) + pos;
    int gi = 0;
    if (wgid >= gp.cum[1]) gi = 1;
    if (wgid >= gp.cum[2]) gi = 2;
    if (wgid >= gp.cum[3]) gi = 3;
    int local = wgid - gp.cum[gi];
    int nbx = gp.nbx[gi];
    int by = local / nbx, bx = local - by * nbx;
    const bf16* A = gp.A[gi];
    const bf16* B = gp.B[gi];
    CT* Cp = (CT*)gp.Cv[gi];
    const float* bias = gp.bias[gi];
    const RT* res = (const RT*)gp.res[gi];
    int M = gp.M[gi], N = gp.N[gi], K = gp.K[gi];
    int lda = gp.lda[gi], ldb = gp.ldb[gi], ldc = gp.ldc[gi];
    int m0 = by * 128, n0 = bx * 128;
    int t = threadIdx.x, lane = t & 63, wv = t >> 6;
    int col = lane & 15, quad = lane >> 4;
    int wm = wv >> 1, wn = wv & 1;
    f32x4 acc[4][4];
    #pragma unroll
    for (int i = 0; i < 4; i++)
        #pragma unroll
        for (int j = 0; j < 4; j++) acc[i][j] = (f32x4){0.f, 0.f, 0.f, 0.f};

    int srow = lane >> 2;
    int scol = ((lane & 3) ^ ((lane >> 3) & 3)) << 3;
    int rslot = (quad ^ ((col >> 1) & 3)) << 3;

    auto stageA = [&](int s3, int kt) {
        int k0 = kt * 32;
        #pragma unroll
        for (int r = 0; r < 2; r++) {
            int R0 = (r * 4 + wv) * 16;
            cp16(A + (long)(m0 + R0 + srow) * lda + k0 + scol, &Asl[s3][R0][0]);
        }
    };
    auto stageB = [&](int s3, int kt) {
        int k0 = kt * 32;
        #pragma unroll
        for (int r = 0; r < 2; r++) {
            int R0 = (r * 4 + wv) * 16;
            cp16(B + (long)(n0 + R0 + srow) * ldb + k0 + scol, &Bsl[s3][R0][0]);
        }
    };

    int nk = K >> 5;
    stageA(0, 0); stageB(0, 0);
    stageA(1, 1); stageB(1, 1);
    __syncthreads();

    for (int kt = 0; kt < nk; kt++) {
        int cur = kt % 3;
        short8 af[4], bf4[4];
        #pragma unroll
        for (int mi = 0; mi < 4; mi++)
            af[mi] = *(const short8*)&Asl[cur][wm * 64 + mi * 16 + col][rslot];
        #pragma unroll
        for (int ni = 0; ni < 4; ni++)
            bf4[ni] = *(const short8*)&Bsl[cur][wn * 64 + ni * 16 + col][rslot];
        bool st = (kt + 2 < nk);
        if (st) {
            int s3 = (kt + 2) % 3;
            stageA(s3, kt + 2); stageB(s3, kt + 2);
        }
        __builtin_amdgcn_s_barrier();
        asm volatile("s_waitcnt lgkmcnt(0)" ::: "memory");
        __builtin_amdgcn_sched_barrier(0);
        __builtin_amdgcn_s_setprio(1);
        #pragma unroll
        for (int mi = 0; mi < 4; mi++)
            #pragma unroll
            for (int ni = 0; ni < 4; ni++)
                acc[mi][ni] = __builtin_amdgcn_mfma_f32_16x16x32_bf16(
                    af[mi], bf4[ni], acc[mi][ni], 0, 0, 0);
        __builtin_amdgcn_s_setprio(0);
        if (kt + 1 < nk) {
            if (st) asm volatile("s_waitcnt vmcnt(4)" ::: "memory");
            else    asm volatile("s_waitcnt vmcnt(0)" ::: "memory");
            __builtin_amdgcn_s_barrier();
        }
    }
    #pragma unroll
    for (int mi = 0; mi < 4; mi++) {
        int gmB = m0 + wm * 64 + mi * 16 + quad * 4;
        #pragma unroll
        for (int ni = 0; ni < 4; ni++) {
            int gn = n0 + wn * 64 + ni * 16 + col;
            if (gn < N) {
                float bz2 = bias ? bias[gn] : 0.f;
                #pragma unroll
                for (int r = 0; r < 4; r++) {
                    int gm = gmB + r;
                    if (gm < M) {
                        float v = acc[mi][ni][r] + bz2;
                        if (dogelu) v = 0.5f * v * (1.f + erff(v * 0.70710678118f));
                        if (res) v += ld1f(res + (long)gm * ldc + gn);
                        st1(Cp + (long)gm * ldc + gn, v);
                    }
                }
            }
        }
    }
}

// ---- grouped row LayerNorm: grid (3136, 4) ----
struct LR4 {
    const bf16* X[4];
    const float* g[4];
    const float* b[4];
    bf16* Y[4];
    int C[4];
};
__global__ __launch_bounds__(256)
void ln_rows4_kernel(LR4 a) {
    __shared__ float x[512];
    __shared__ float red[4];
    int br = blockIdx.y;
    long row = blockIdx.x;
    int C = a.C[br];
    int t = threadIdx.x;
    const bf16* xr = a.X[br] + row * C;
    float s = 0.f, q = 0.f;
    for (int i = t; i < C; i += 256) { float v = ld1f(xr + i); x[i] = v; s += v; q += v * v; }
    float S1 = blockSum256(s, red), S2 = blockSum256(q, red);
    float mu = S1 / C;
    float r = rsqrtf(S2 / C - mu * mu + 1e-6f);
    const float* g = a.g[br];
    const float* b = a.b[br];
    bf16* y = a.Y[br] + row * C;
    for (int i = t; i < C; i += 256)
        st1(y + i, (x[i] - mu) * r * g[i] + b[i]);
}

// ---- grouped softmax over last dim (960); rstd from fused stats ----
struct SMX {
    bf16* S[4];
    const float* stat[4];
    int C[4];
    int cum[5];
};
__global__ __launch_bounds__(256)
void softmax_all_kernel(SMX a) {
    __shared__ float x[960];
    __shared__ float red[4];
    int rid = blockIdx.x;
    int gi = 0;
    if (rid >= a.cum[1]) gi = 1;
    if (rid >= a.cum[2]) gi = 2;
    if (rid >= a.cum[3]) gi = 3;
    int local = rid - a.cum[gi];
    int C = a.C[gi];
    int z = local / C;
    int d = local - z * C;
    int t = threadIdx.x;
    float n = 960.f * (float)C;
    float s0 = a.stat[gi][2 * z], q0 = a.stat[gi][2 * z + 1];
    float mu = s0 / n;
    float rs = rsqrtf(q0 / n - mu * mu + 1e-5f);
    int h = z & 3, b = z >> 2;
    bf16* row = a.S[gi] + (long)b * C * 3840 + (long)d * 3840 + h * 960;
    float mx = -3.4e38f;
    for (int i = t; i < 960; i += 256) {
        float v = ld1f(row + i) * rs; x[i] = v; mx = fmaxf(mx, v);
    }
    float M = blockMax256(mx, red);
    float s = 0.f;
    for (int i = t; i < 960; i += 256) { float e = __expf(x[i] - M); x[i] = e; s += e; }
    float Ssum = blockSum256(s, red);
    float inv = 1.f / Ssum;
    for (int i = t; i < 960; i += 256) st1(row + i, x[i] * inv);
}

extern "C" void kernel_launch(void* const* d_in, const int* in_sizes, int n_in,
                              void* d_out, int out_size, void* d_ws, size_t ws_size,
                              hipStream_t stream) {
    (void)in_sizes; (void)n_in; (void)out_size; (void)ws_size;
    const int Cs[4] = {64, 128, 256, 512};
    const float *emb[4], *ang[4], *anb[4], *Wq[4], *Wo[4], *fng[4], *fnb[4], *w1[4], *b1[4], *w2[4], *b2[4];
    for (int i = 0; i < 4; i++) {
        const int base = i * 11;
        emb[i] = (const float*)d_in[base + 0];
        ang[i] = (const float*)d_in[base + 1];
        anb[i] = (const float*)d_in[base + 2];
        Wq[i]  = (const float*)d_in[base + 3];
        Wo[i]  = (const float*)d_in[base + 4];
        fng[i] = (const float*)d_in[base + 5];
        fnb[i] = (const float*)d_in[base + 6];
        w1[i]  = (const float*)d_in[base + 7];
        b1[i]  = (const float*)d_in[base + 8];
        w2[i]  = (const float*)d_in[base + 9];
        b2[i]  = (const float*)d_in[base + 10];
    }
    const float* anAg = (const float*)d_in[44];
    const float* anAb = (const float*)d_in[45];
    const float* Wk   = (const float*)d_in[46];
    const float* Wv   = (const float*)d_in[47];

    const int NT = 3136;
    char* wsb = (char*)d_ws;
    // ---- layout (bytes); phase-liveness overlays:
    //   R1 (9.05M..33.14M): KT (ph2 write, ph4 read) -> hid (ph11 write)
    //   R2 (33.14M..57.22M): Vb2 (ph2 write, ph8 read) -> xball(ph9)/cx3(ph10)
    //   QTp (57.22M..70.07M): wkv(early) -> QT512(4a) -> QTrest(4c) -> cx2(ph8)
    //   S5  (70.07M..85.8M): ea(early) -> S(C=512)(4b)
    //   SR  (85.8M..99.55M): cxall(early) -> S rest(4d)
    unsigned short* wp = (unsigned short*)(wsb);          // 0..9,052,160
    float* statb = (float*)(wsb + 9052160);               // 128 floats
    bf16*  KT    = (bf16*)(wsb + 9053184);                // [3840][3136] 24.08M
    bf16*  hid   = KT;                                    // FFN hid (over KT)
    bf16*  Vb2   = (bf16*)(wsb + 33137664);               // [3136][3840] 24.08M
    bf16*  xball = (bf16*)(wsb + 33137664);               // (over Vb2, ph9+)
    bf16*  cx3   = (bf16*)(wsb + 39158784);               // (over Vb2, ph10+)
    bf16*  QTp   = (bf16*)(wsb + 57222144);               // QT pool 12.85M
    bf16*  wkv   = (bf16*)(wsb + 57222144);               // [7680][960] early
    bf16*  cx2   = (bf16*)(wsb + 57222144);               // ctx (over QTp, ph8+)
    bf16*  S5    = (bf16*)(wsb + 70067200);               // S(C=512) 15.73M
    bf16*  ea    = (bf16*)(wsb + 71967744);               // early (inside S5)
    bf16*  SR    = (bf16*)(wsb + 85795840);               // S rest 13.76M
    bf16*  cxall = (bf16*)(wsb + 85795840);               // early (inside SR)

    const long wb[4]  = {0, 53248, 266240, 1118208};      // weight pool prefix
    const long co[4]  = {0, 200704, 602112, 1404928};     // [NT][C] offsets
    const long ho[4]  = {0, 802816, 2408448, 5619712};    // hid offsets
    const long qro[3] = {4816896, 3211264, 0};            // QTrest: i=0,1,2
    const long sro[3] = {5898240, 3932160, 0};            // SRest:  i=0,1,2

    float* out = (float*)d_out;
    const float scale = 0.03227486121f;  // 1/sqrt(960)

    // ---- 1) prep: all weights -> bf16 + zero stats + merged LayerNorms ----
    {
        Prep p;
        p.cv.s[0] = Wk; p.cv.d[0] = (unsigned short*)wkv;           p.cv.n[0] = 3686400;
        p.cv.s[1] = Wv; p.cv.d[1] = (unsigned short*)wkv + 3686400; p.cv.n[1] = 3686400;
        for (int i = 0; i < 4; i++) {
            const long C2 = (long)Cs[i] * Cs[i];
            p.cv.s[2 + 4 * i] = Wq[i]; p.cv.d[2 + 4 * i] = wp + wb[i];          p.cv.n[2 + 4 * i] = 4 * C2;
            p.cv.s[3 + 4 * i] = Wo[i]; p.cv.d[3 + 4 * i] = wp + wb[i] + 4 * C2; p.cv.n[3 + 4 * i] = C2;
            p.cv.s[4 + 4 * i] = w1[i]; p.cv.d[4 + 4 * i] = wp + wb[i] + 5 * C2; p.cv.n[4 + 4 * i] = 4 * C2;
            p.cv.s[5 + 4 * i] = w2[i]; p.cv.d[5 + 4 * i] = wp + wb[i] + 9 * C2; p.cv.n[5 + 4 * i] = 4 * C2;
        }
        p.cv.z = statb;
        for (int i = 0; i < 4; i++) {
            p.ln.e[i] = emb[i]; p.ln.ag[i] = ang[i]; p.ln.ab[i] = anb[i];
            p.ln.y[i] = cxall + co[i];
        }
        p.ln.cg = anAg; p.ln.cbb = anAb; p.ln.ea = ea;
        prep_kernel<<<4160, 256, 0, stream>>>(p);
    }
    // ---- 2) fused K+V projection ----
    mfma8kv<<<dim3(32, 14, 1), 512, 0, stream>>>(ea, wkv, KT, Vb2);

    // ---- 3) Qproj C=512 -> QTp ----
    mfma4<bf16, float, true><<<dim3(4, 26, 4), 256, 0, stream>>>(
        cxall + co[3], 0, 0, 512, (const bf16*)(wp + wb[3]), 262144, 0, 512,
        QTp, 512L * NT, 0, NT,
        nullptr, (const float*)nullptr, NT, 512, 512, 3328, 512, 0, 0,
        1.f, 0, nullptr);
    // ---- 4) S C=512 (+stats) -> S5 ----
    mfma4<bf16, float, false><<<dim3(8, 4, 16), 256, 0, stream>>>(
        QTp, 512L * NT, 784, NT, KT, 3010560, 784, NT,
        S5, 960, 512L * 3840, 3840,
        nullptr, (const float*)nullptr, 512, 960, 784, 512, 1024, 0, 0,
        scale, 0, statb + 32 * 3);
    // ---- 5) Qproj rest (C=256,128,64) grouped -> QTp ----
    {
        GZ g;
        int cum = 0;
        const int ord[3] = {2, 1, 0};
        for (int j = 0; j < 3; j++) {
            int i = ord[j], C = Cs[i];
            g.A[j] = cxall + co[i]; g.Ah[j] = 0; g.Ab[j] = 0; g.lda[j] = C;
            g.B[j] = (const bf16*)(wp + wb[i]); g.Bh[j] = (long)C * C; g.Bb[j] = 0; g.ldb[j] = C;
            g.C[j] = QTp + qro[i]; g.Ch[j] = (long)C * NT; g.Cb[j] = 0; g.ldc[j] = NT;
            g.M[j] = NT; g.N[j] = C; g.K[j] = C;
            g.Mpad[j] = 3328; g.Npad[j] = (C >= 128) ? C : 64;
            g.nbx[j] = (C >= 128) ? C / 128 : 1; g.nby[j] = 26;
            g.alpha[j] = 1.f; g.stat[j] = nullptr;
            g.cum[j] = cum; cum += g.nbx[j] * 26 * 4;
        }
        g.cum[3] = cum; g.cum[4] = cum;
        mfmaGZ<true><<<cum, 256, 0, stream>>>(g);
    }
    // ---- 6) S rest grouped (+stats) -> SR ----
    {
        GZ g;
        int cum = 0;
        const int ord[3] = {2, 1, 0};
        for (int j = 0; j < 3; j++) {
            int i = ord[j], C = Cs[i];
            g.A[j] = QTp + qro[i]; g.Ah[j] = (long)C * NT; g.Ab[j] = 784; g.lda[j] = NT;
            g.B[j] = KT; g.Bh[j] = 3010560; g.Bb[j] = 784; g.ldb[j] = NT;
            g.C[j] = SR + sro[i]; g.Ch[j] = 960; g.Cb[j] = (long)C * 3840; g.ldc[j] = 3840;
            g.M[j] = C; g.N[j] = 960; g.K[j] = 784;
            g.Mpad[j] = (C >= 128) ? C : 64; g.Npad[j] = 1024;
            g.nbx[j] = 8; g.nby[j] = (C >= 128) ? C / 128 : 1;
            g.alpha[j] = scale; g.stat[j] = statb + 32 * i;
            g.cum[j] = cum; cum += 8 * g.nby[j] * 16;
        }
        g.cum[3] = cum; g.cum[4] = cum;
        mfmaGZ<false><<<cum, 256, 0, stream>>>(g);
    }
    // ---- 7) softmax all branches ----
    {
        SMX a;
        const int ord[4] = {3, 2, 1, 0};
        int cum = 0;
        for (int j = 0; j < 4; j++) {
            int i = ord[j], C = Cs[i];
            a.S[j] = (i == 3) ? S5 : SR + sro[i];
            a.stat[j] = statb + 32 * i;
            a.C[j] = C;
            a.cum[j] = cum; cum += 16 * C;
        }
        a.cum[4] = cum;
        softmax_all_kernel<<<cum, 256, 0, stream>>>(a);
    }
    // ---- 8) PV-direct: ctx = 0.25 * Vb2 @ S[b]^T (K=3840), all branches ----
    {
        GZ g;
        int cum = 0;
        const int ord[4] = {3, 2, 1, 0};
        for (int j = 0; j < 4; j++) {
            int i = ord[j], C = Cs[i];
            g.A[j] = Vb2; g.Ah[j] = 784L * 3840; g.Ab[j] = 0; g.lda[j] = 3840;
            g.B[j] = (i == 3) ? S5 : SR + sro[i];
            g.Bh[j] = (long)C * 3840; g.Bb[j] = 0; g.ldb[j] = 3840;
            g.C[j] = cx2 + co[i]; g.Ch[j] = 784L * C; g.Cb[j] = 0; g.ldc[j] = C;
            g.M[j] = 784; g.N[j] = C; g.K[j] = 3840;
            g.Mpad[j] = 896; g.Npad[j] = (C >= 128) ? C : 64;
            g.nbx[j] = (C >= 128) ? C / 128 : 1; g.nby[j] = 7;
            g.alpha[j] = 0.25f; g.stat[j] = nullptr;
            g.cum[j] = cum; cum += g.nbx[j] * 7 * 4;
        }
        g.cum[4] = cum;
        mfmaGZ<false><<<cum, 256, 0, stream>>>(g);
    }
    // ---- 9) grouped Wo-all: xb = emb + ctx @ Wo^T ----
    {
        G4 g;
        int cum = 0;
        for (int i = 0; i < 4; i++) {
            const int C = Cs[i];
            const long C2 = (long)C * C;
            g.A[i] = cx2 + co[i]; g.B[i] = (const bf16*)(wp + wb[i] + 4 * C2);
            g.Cv[i] = xball + co[i];
            g.bias[i] = nullptr; g.res[i] = emb[i];
            g.M[i] = NT; g.N[i] = C; g.K[i] = C;
            g.lda[i] = C; g.ldb[i] = C; g.ldc[i] = C;
            g.nbx[i] = (C >= 128) ? C / 128 : 1;
            g.cum[i] = cum; cum += g.nbx[i] * 26;
        }
        g.cum[4] = cum;
        mfma4g<bf16, float><<<cum, 256, 0, stream>>>(g, 0);
    }
    // ---- 10) grouped LN ----
    {
        LR4 a;
        for (int i = 0; i < 4; i++) {
            a.X[i] = xball + co[i]; a.g[i] = fng[i]; a.b[i] = fnb[i];
            a.Y[i] = cx3 + co[i]; a.C[i] = Cs[i];
        }
        ln_rows4_kernel<<<dim3(3136, 4), 256, 0, stream>>>(a);
    }
    // ---- 11) grouped FFN1: hid = gelu(lnx @ w1^T + b1) ----
    {
        G4 g;
        int cum = 0;
        for (int i = 0; i < 4; i++) {
            const int C = Cs[i];
            const long C2 = (long)C * C;
            g.A[i] = cx3 + co[i]; g.B[i] = (const bf16*)(wp + wb[i] + 5 * C2);
            g.Cv[i] = hid + ho[i];
            g.bias[i] = b1[i]; g.res[i] = nullptr;
            g.M[i] = NT; g.N[i] = 4 * C; g.K[i] = C;
            g.lda[i] = C; g.ldb[i] = C; g.ldc[i] = 4 * C;
            g.nbx[i] = 4 * C / 128;
            g.cum[i] = cum; cum += g.nbx[i] * 26;
        }
        g.cum[4] = cum;
        mfma4g<bf16, float><<<cum, 256, 0, stream>>>(g, 1);
    }
    // ---- 12) grouped FFN2: out = xb + hid @ w2^T + b2 (fp32) ----
    {
        G4 g;
        int cum = 0;
        for (int i = 0; i < 4; i++) {
            const int C = Cs[i];
            const long C2 = (long)C * C;
            g.A[i] = hid + ho[i]; g.B[i] = (const bf16*)(wp + wb[i] + 9 * C2);
            g.Cv[i] = out + co[i];
            g.bias[i] = b2[i]; g.res[i] = xball + co[i];
            g.M[i] = NT; g.N[i] = C; g.K[i] = 4 * C;
            g.lda[i] = 4 * C; g.ldb[i] = 4 * C; g.ldc[i] = C;
            g.nbx[i] = (C >= 128) ? C / 128 : 1;
            g.cum[i] = cum; cum += g.nbx[i] * 26;
        }
        g.cum[4] = cum;
        mfma4g<float, bf16><<<cum, 256, 0, stream>>>(g, 0);
    }
}